// Round 16
// baseline (31.553 us; speedup 1.0000x reference)
//
#include <hip/hip_runtime.h>

#define H_    1024
#define B_    512
#define OUT_  512
#define SLAB_ ((size_t)B_ * 3072)   // halves per K-partial slab

typedef _Float16 half8 __attribute__((ext_vector_type(8)));
typedef _Float16 half4 __attribute__((ext_vector_type(4)));
typedef float    f32x4 __attribute__((ext_vector_type(4)));

__device__ __forceinline__ half8 cvt8(float4 lo, float4 hi) {
    half8 h;
    h[0] = (_Float16)lo.x; h[1] = (_Float16)lo.y; h[2] = (_Float16)lo.z; h[3] = (_Float16)lo.w;
    h[4] = (_Float16)hi.x; h[5] = (_Float16)hi.y; h[6] = (_Float16)hi.z; h[7] = (_Float16)hi.w;
    return h;
}

// Workgroup barrier WITHOUT the vmcnt(0) drain __syncthreads() emits.
__device__ __forceinline__ void barrier_nodrain() {
    asm volatile("s_waitcnt lgkmcnt(0)" ::: "memory");
    __builtin_amdgcn_s_barrier();
}

// ===========================================================================
// qkv (R12/R15-proven): 64x64 tiles, BK=64, 8 K-steps (unrolled), K-split x2,
// 4 waves (2x2, each 32x32), 768 blocks, XCD-chunked bm-fastest decode.
// Output: f16 partials qkvph[kz][B][3072]. T5: setprio(1) around MFMA
// cluster (phase-staggered blocks/CU -> scheduler has roles to arbitrate).
// ===========================================================================
__global__ __launch_bounds__(256) void qkv_kernel(const float* __restrict__ x,
                                                  const float* __restrict__ Wq,
                                                  const float* __restrict__ Wk,
                                                  const float* __restrict__ Wv,
                                                  _Float16* __restrict__ qkvph)
{
    __shared__ __align__(16) _Float16 sA[2][64 * 64];
    __shared__ __align__(16) _Float16 sB[2][64 * 64];

    const int tid  = threadIdx.x;
    const int lane = tid & 63;
    const int w    = tid >> 6;
    const int wr   = w >> 1, wc = w & 1;
    const int fr   = lane & 15, fg = lane >> 4;

    // XCD-chunked job swizzle (768 = 8 * 96, bijective), bm fastest
    const int d    = blockIdx.x;
    const int job  = (d & 7) * 96 + (d >> 3);
    const int bm   = (job & 7) * 64;
    const int rest = job >> 3;                 // 0..95
    const int kz   = (rest >= 48) ? 1 : 0;
    const int bn   = (rest - kz * 48) * 64;    // 0..3071
    const int k0   = kz * 512;

    const int wsel = bn >> 10;
    const float* W = (wsel == 0) ? Wq : (wsel == 1) ? Wk : Wv;
    const int brow = bn & 1023;

    const int srow = tid >> 2;
    const int cq   = tid & 3;
    const float* Ap = x + (size_t)(bm + srow) * H_ + k0 + cq * 16;
    const float* Bp = W + (size_t)(brow + srow) * H_ + k0 + cq * 16;

    const int g0    = (((2 * cq)     ^ (srow & 7)) << 3);
    const int g1    = (((2 * cq + 1) ^ (srow & 7)) << 3);
    const int wbase = srow * 64;

    f32x4 acc[2][2] = {};

    float4 a0 = *(const float4*)(Ap + 0), a1 = *(const float4*)(Ap + 4);
    float4 a2 = *(const float4*)(Ap + 8), a3 = *(const float4*)(Ap + 12);
    float4 b0 = *(const float4*)(Bp + 0), b1 = *(const float4*)(Bp + 4);
    float4 b2 = *(const float4*)(Bp + 8), b3 = *(const float4*)(Bp + 12);

#pragma unroll
    for (int t = 0; t < 8; ++t) {
        const int buf = t & 1;
        half8 hA0 = cvt8(a0, a1), hA1 = cvt8(a2, a3);
        half8 hB0 = cvt8(b0, b1), hB1 = cvt8(b2, b3);
        if (t < 7) {
            const float* An = Ap + (t + 1) * 64;
            const float* Bn = Bp + (t + 1) * 64;
            a0 = *(const float4*)(An + 0); a1 = *(const float4*)(An + 4);
            a2 = *(const float4*)(An + 8); a3 = *(const float4*)(An + 12);
            b0 = *(const float4*)(Bn + 0); b1 = *(const float4*)(Bn + 4);
            b2 = *(const float4*)(Bn + 8); b3 = *(const float4*)(Bn + 12);
        }
        *(half8*)&sA[buf][wbase + g0] = hA0;
        *(half8*)&sA[buf][wbase + g1] = hA1;
        *(half8*)&sB[buf][wbase + g0] = hB0;
        *(half8*)&sB[buf][wbase + g1] = hB1;
        barrier_nodrain();

        __builtin_amdgcn_s_setprio(1);
#pragma unroll
        for (int kh = 0; kh < 2; ++kh) {
            const int p = (((kh * 4 + fg) ^ (fr & 7)) << 3);
            half8 af[2], bf[2];
#pragma unroll
            for (int mi = 0; mi < 2; ++mi)
                af[mi] = *(const half8*)&sA[buf][(wr * 32 + mi * 16 + fr) * 64 + p];
#pragma unroll
            for (int ni = 0; ni < 2; ++ni)
                bf[ni] = *(const half8*)&sB[buf][(wc * 32 + ni * 16 + fr) * 64 + p];
#pragma unroll
            for (int mi = 0; mi < 2; ++mi)
#pragma unroll
                for (int ni = 0; ni < 2; ++ni)
                    acc[mi][ni] = __builtin_amdgcn_mfma_f32_16x16x32_f16(
                                      af[mi], bf[ni], acc[mi][ni], 0, 0, 0);
        }
        __builtin_amdgcn_s_setprio(0);
    }

    _Float16* Cb = qkvph + (size_t)kz * SLAB_ + (size_t)bm * 3072 + bn;
#pragma unroll
    for (int mi = 0; mi < 2; ++mi) {
        const int r0 = wr * 32 + mi * 16 + fg * 4;
#pragma unroll
        for (int ni = 0; ni < 2; ++ni) {
            const int col = wc * 32 + ni * 16 + fr;
#pragma unroll
            for (int r = 0; r < 4; ++r)
                Cb[(size_t)(r0 + r) * 3072 + col] = (_Float16)acc[mi][ni][r];
        }
    }
}

// ===========================================================================
// attn: Taylor moments (deg 7) + Horner eval from 2 f16 K-partials (+bv).
// ALSO initializes out-row b to bo (so out_kernel can pure-atomicAdd).
// ===========================================================================
__global__ __launch_bounds__(256) void attn_kernel(const _Float16* __restrict__ qkvph,
                                                   const float* __restrict__ bv,
                                                   const float* __restrict__ bo,
                                                   _Float16* __restrict__ attnh,
                                                   float* __restrict__ outp)
{
    __shared__ float red[4][16];
    __shared__ float sm[16];
    const int b   = blockIdx.x;
    const int tid = threadIdx.x;
    const _Float16* p0 = qkvph + (size_t)b * 3072;
    const _Float16* p1 = p0 + SLAB_;

    // init out row b = bo (128 float4 writes by threads 0..127)
    if (tid < 128)
        ((float4*)(outp + (size_t)b * OUT_))[tid] = ((const float4*)bo)[tid];

    half4 ka = ((const half4*)(p0 + 1024))[tid];
    half4 kb = ((const half4*)(p1 + 1024))[tid];
    half4 va = ((const half4*)(p0 + 2048))[tid];
    half4 vb = ((const half4*)(p1 + 2048))[tid];
    float4 bv4 = ((const float4*)bv)[tid];

    const float ks[4] = {(float)ka[0] + (float)kb[0], (float)ka[1] + (float)kb[1],
                         (float)ka[2] + (float)kb[2], (float)ka[3] + (float)kb[3]};
    const float vs[4] = {(float)va[0] + (float)vb[0] + bv4.x,
                         (float)va[1] + (float)vb[1] + bv4.y,
                         (float)va[2] + (float)vb[2] + bv4.z,
                         (float)va[3] + (float)vb[3] + bv4.w};

    float m[8] = {}, Mv[8] = {};
#pragma unroll
    for (int e = 0; e < 4; ++e) {
        float s = ks[e] * (1.0f / 32.0f);
        float v = vs[e];
        float p = 1.0f;
#pragma unroll
        for (int n = 0; n < 8; ++n) {
            m[n] += p;
            Mv[n] = fmaf(p, v, Mv[n]);
            p *= s;
        }
    }
#pragma unroll
    for (int off = 32; off; off >>= 1)
#pragma unroll
        for (int n = 0; n < 8; ++n) {
            m[n]  += __shfl_xor(m[n],  off, 64);
            Mv[n] += __shfl_xor(Mv[n], off, 64);
        }
    const int wave = tid >> 6;
    if ((tid & 63) == 0) {
#pragma unroll
        for (int n = 0; n < 8; ++n) {
            red[wave][n]     = m[n];
            red[wave][n + 8] = Mv[n];
        }
    }
    __syncthreads();
    if (tid < 16) {
        const float invfact[8] = {1.f, 1.f, 0.5f, 1.f/6.f, 1.f/24.f,
                                  1.f/120.f, 1.f/720.f, 1.f/5040.f};
        sm[tid] = (red[0][tid] + red[1][tid] + red[2][tid] + red[3][tid])
                  * invfact[tid & 7];
    }
    __syncthreads();

    half4 qa = ((const half4*)p0)[tid];
    half4 qb = ((const half4*)p1)[tid];
    half4 o;
#pragma unroll
    for (int e = 0; e < 4; ++e) {
        float c = (float)qa[e] + (float)qb[e];
        float den = sm[7];
#pragma unroll
        for (int n = 6; n >= 0; --n) den = fmaf(den, c, sm[n]);
        float num = sm[15];
#pragma unroll
        for (int n = 14; n >= 8; --n) num = fmaf(num, c, sm[n]);
        o[e] = (_Float16)(num / den);
    }
    ((half4*)attnh)[b * 256 + tid] = o;
}

// ===========================================================================
// out += attn @ Wo^T (bias pre-initialized by attn_kernel). BM=BN=32,
// K-split x2 -> 512 blocks (2/CU), 8 steps (unrolled), f32 atomicAdd
// epilogue (exactly 2 commutative adds per element -> deterministic).
// T5 setprio around MFMA.
// ===========================================================================
__global__ __launch_bounds__(256) void out_kernel(const _Float16* __restrict__ attnh,
                                                  const float* __restrict__ Wo,
                                                  float* __restrict__ outp)
{
    __shared__ __align__(16) _Float16 sA[2][32 * 64];
    __shared__ __align__(16) _Float16 sB[2][32 * 64];

    const int tid  = threadIdx.x;
    const int lane = tid & 63;
    const int w    = tid >> 6;
    const int wr   = w >> 1, wc = w & 1;
    const int fr   = lane & 15, fg = lane >> 4;

    // 512 = 8 xcd * 64 jobs; job = {16 bm (fast) x 4 bn}; kz = xcd&1
    const int d   = blockIdx.x;
    const int xcd = d & 7;
    const int j   = d >> 3;                  // 0..63
    const int kz  = xcd & 1;
    const int bm  = (j & 15) * 32;
    const int bn  = ((xcd >> 1) * 4 + (j >> 4)) * 32;   // 0..480
    const int k0  = kz * 512;

    const int srow = tid >> 3;
    const int cg_  = tid & 7;
    const _Float16* Ap = attnh + (size_t)(bm + srow) * H_ + k0 + cg_ * 8;
    const float*    Bp = Wo    + (size_t)(bn + srow) * H_ + k0 + cg_ * 8;

    const int sw    = (cg_ ^ (srow & 7)) << 3;
    const int wbase = srow * 64;

    f32x4 acc = {};

    half8  a0 = *(const half8*)Ap;
    float4 b0 = *(const float4*)(Bp + 0), b1 = *(const float4*)(Bp + 4);

#pragma unroll
    for (int t = 0; t < 8; ++t) {
        const int buf = t & 1;
        half8 hA = a0;
        half8 hB = cvt8(b0, b1);
        if (t < 7) {
            a0 = *(const half8*)(Ap + (t + 1) * 64);
            b0 = *(const float4*)(Bp + (t + 1) * 64);
            b1 = *(const float4*)(Bp + (t + 1) * 64 + 4);
        }
        *(half8*)&sA[buf][wbase + sw] = hA;
        *(half8*)&sB[buf][wbase + sw] = hB;
        barrier_nodrain();

        __builtin_amdgcn_s_setprio(1);
#pragma unroll
        for (int kh = 0; kh < 2; ++kh) {
            const int p = (((kh * 4 + fg) ^ (fr & 7)) << 3);
            half8 af = *(const half8*)&sA[buf][(wr * 16 + fr) * 64 + p];
            half8 bf = *(const half8*)&sB[buf][(wc * 16 + fr) * 64 + p];
            acc = __builtin_amdgcn_mfma_f32_16x16x32_f16(af, bf, acc, 0, 0, 0);
        }
        __builtin_amdgcn_s_setprio(0);
    }

    const int row0 = bm + wr * 16 + fg * 4;
    const int col  = bn + wc * 16 + fr;
#pragma unroll
    for (int r = 0; r < 4; ++r)
        atomicAdd(&outp[(size_t)(row0 + r) * OUT_ + col], acc[r]);
}

extern "C" void kernel_launch(void* const* d_in, const int* in_sizes, int n_in,
                              void* d_out, int out_size, void* d_ws, size_t ws_size,
                              hipStream_t stream)
{
    const float* x  = (const float*)d_in[0];
    const float* Wq = (const float*)d_in[1];
    const float* Wk = (const float*)d_in[2];
    const float* Wv = (const float*)d_in[3];
    const float* bv = (const float*)d_in[4];
    const float* Wo = (const float*)d_in[5];
    const float* bo = (const float*)d_in[6];
    float* out = (float*)d_out;

    char* ws = (char*)d_ws;
    _Float16* qkvph = (_Float16*)ws;                 // [2][512][3072] f16 = 6.3 MB
    _Float16* attnh = (_Float16*)(ws + (8 << 20));   // [512][1024] f16 = 1 MB

    qkv_kernel<<<dim3(768), 256, 0, stream>>>(x, Wq, Wk, Wv, qkvph);
    attn_kernel<<<dim3(B_), 256, 0, stream>>>(qkvph, bv, bo, attnh, out);
    out_kernel<<<dim3(512), 256, 0, stream>>>(attnh, Wo, out);
}

// Round 17
// 30.196 us; speedup vs baseline: 1.0450x; 1.0450x over previous
//
#include <hip/hip_runtime.h>

#define H_    1024
#define B_    512
#define OUT_  512
#define SLAB_ ((size_t)B_ * 3072)   // halves per K-partial slab

typedef _Float16 half8 __attribute__((ext_vector_type(8)));
typedef _Float16 half4 __attribute__((ext_vector_type(4)));
typedef float    f32x4 __attribute__((ext_vector_type(4)));

__device__ __forceinline__ half8 cvt8(float4 lo, float4 hi) {
    half8 h;
    h[0] = (_Float16)lo.x; h[1] = (_Float16)lo.y; h[2] = (_Float16)lo.z; h[3] = (_Float16)lo.w;
    h[4] = (_Float16)hi.x; h[5] = (_Float16)hi.y; h[6] = (_Float16)hi.z; h[7] = (_Float16)hi.w;
    return h;
}

// Workgroup barrier WITHOUT the vmcnt(0) drain __syncthreads() emits.
__device__ __forceinline__ void barrier_nodrain() {
    asm volatile("s_waitcnt lgkmcnt(0)" ::: "memory");
    __builtin_amdgcn_s_barrier();
}

// ===========================================================================
// qkv (R15-proven optimum): 64x64 tiles, BK=64, 8 K-steps (unrolled),
// K-split x2, 4 waves (2x2, each 32x32), 768 blocks, XCD-chunked decode.
// Output: f16 partials qkvph[kz][B][3072].
// ===========================================================================
__global__ __launch_bounds__(256) void qkv_kernel(const float* __restrict__ x,
                                                  const float* __restrict__ Wq,
                                                  const float* __restrict__ Wk,
                                                  const float* __restrict__ Wv,
                                                  _Float16* __restrict__ qkvph)
{
    __shared__ __align__(16) _Float16 sA[2][64 * 64];
    __shared__ __align__(16) _Float16 sB[2][64 * 64];

    const int tid  = threadIdx.x;
    const int lane = tid & 63;
    const int w    = tid >> 6;
    const int wr   = w >> 1, wc = w & 1;
    const int fr   = lane & 15, fg = lane >> 4;

    // XCD-chunked job swizzle (768 = 8 * 96, bijective), bm fastest
    const int d    = blockIdx.x;
    const int job  = (d & 7) * 96 + (d >> 3);
    const int bm   = (job & 7) * 64;
    const int rest = job >> 3;                 // 0..95
    const int kz   = (rest >= 48) ? 1 : 0;
    const int bn   = (rest - kz * 48) * 64;    // 0..3071
    const int k0   = kz * 512;

    const int wsel = bn >> 10;
    const float* W = (wsel == 0) ? Wq : (wsel == 1) ? Wk : Wv;
    const int brow = bn & 1023;

    const int srow = tid >> 2;
    const int cq   = tid & 3;
    const float* Ap = x + (size_t)(bm + srow) * H_ + k0 + cq * 16;
    const float* Bp = W + (size_t)(brow + srow) * H_ + k0 + cq * 16;

    const int g0    = (((2 * cq)     ^ (srow & 7)) << 3);
    const int g1    = (((2 * cq + 1) ^ (srow & 7)) << 3);
    const int wbase = srow * 64;

    f32x4 acc[2][2] = {};

    float4 a0 = *(const float4*)(Ap + 0), a1 = *(const float4*)(Ap + 4);
    float4 a2 = *(const float4*)(Ap + 8), a3 = *(const float4*)(Ap + 12);
    float4 b0 = *(const float4*)(Bp + 0), b1 = *(const float4*)(Bp + 4);
    float4 b2 = *(const float4*)(Bp + 8), b3 = *(const float4*)(Bp + 12);

#pragma unroll
    for (int t = 0; t < 8; ++t) {
        const int buf = t & 1;
        half8 hA0 = cvt8(a0, a1), hA1 = cvt8(a2, a3);
        half8 hB0 = cvt8(b0, b1), hB1 = cvt8(b2, b3);
        if (t < 7) {
            const float* An = Ap + (t + 1) * 64;
            const float* Bn = Bp + (t + 1) * 64;
            a0 = *(const float4*)(An + 0); a1 = *(const float4*)(An + 4);
            a2 = *(const float4*)(An + 8); a3 = *(const float4*)(An + 12);
            b0 = *(const float4*)(Bn + 0); b1 = *(const float4*)(Bn + 4);
            b2 = *(const float4*)(Bn + 8); b3 = *(const float4*)(Bn + 12);
        }
        *(half8*)&sA[buf][wbase + g0] = hA0;
        *(half8*)&sA[buf][wbase + g1] = hA1;
        *(half8*)&sB[buf][wbase + g0] = hB0;
        *(half8*)&sB[buf][wbase + g1] = hB1;
        barrier_nodrain();

#pragma unroll
        for (int kh = 0; kh < 2; ++kh) {
            const int p = (((kh * 4 + fg) ^ (fr & 7)) << 3);
            half8 af[2], bf[2];
#pragma unroll
            for (int mi = 0; mi < 2; ++mi)
                af[mi] = *(const half8*)&sA[buf][(wr * 32 + mi * 16 + fr) * 64 + p];
#pragma unroll
            for (int ni = 0; ni < 2; ++ni)
                bf[ni] = *(const half8*)&sB[buf][(wc * 32 + ni * 16 + fr) * 64 + p];
#pragma unroll
            for (int mi = 0; mi < 2; ++mi)
#pragma unroll
                for (int ni = 0; ni < 2; ++ni)
                    acc[mi][ni] = __builtin_amdgcn_mfma_f32_16x16x32_f16(
                                      af[mi], bf[ni], acc[mi][ni], 0, 0, 0);
        }
    }

    _Float16* Cb = qkvph + (size_t)kz * SLAB_ + (size_t)bm * 3072 + bn;
#pragma unroll
    for (int mi = 0; mi < 2; ++mi) {
        const int r0 = wr * 32 + mi * 16 + fg * 4;
#pragma unroll
        for (int ni = 0; ni < 2; ++ni) {
            const int col = wc * 32 + ni * 16 + fr;
#pragma unroll
            for (int r = 0; r < 4; ++r)
                Cb[(size_t)(r0 + r) * 3072 + col] = (_Float16)acc[mi][ni][r];
        }
    }
}

// ===========================================================================
// attn: Taylor moments (deg 7) + Horner eval from 2 f16 K-partials (+bv).
// ALSO initializes out-row b to bo (so out_kernel can pure-atomicAdd).
// ===========================================================================
__global__ __launch_bounds__(256) void attn_kernel(const _Float16* __restrict__ qkvph,
                                                   const float* __restrict__ bv,
                                                   const float* __restrict__ bo,
                                                   _Float16* __restrict__ attnh,
                                                   float* __restrict__ outp)
{
    __shared__ float red[4][16];
    __shared__ float sm[16];
    const int b   = blockIdx.x;
    const int tid = threadIdx.x;
    const _Float16* p0 = qkvph + (size_t)b * 3072;
    const _Float16* p1 = p0 + SLAB_;

    // init out row b = bo (128 float4 writes by threads 0..127)
    if (tid < 128)
        ((float4*)(outp + (size_t)b * OUT_))[tid] = ((const float4*)bo)[tid];

    half4 ka = ((const half4*)(p0 + 1024))[tid];
    half4 kb = ((const half4*)(p1 + 1024))[tid];
    half4 va = ((const half4*)(p0 + 2048))[tid];
    half4 vb = ((const half4*)(p1 + 2048))[tid];
    float4 bv4 = ((const float4*)bv)[tid];

    const float ks[4] = {(float)ka[0] + (float)kb[0], (float)ka[1] + (float)kb[1],
                         (float)ka[2] + (float)kb[2], (float)ka[3] + (float)kb[3]};
    const float vs[4] = {(float)va[0] + (float)vb[0] + bv4.x,
                         (float)va[1] + (float)vb[1] + bv4.y,
                         (float)va[2] + (float)vb[2] + bv4.z,
                         (float)va[3] + (float)vb[3] + bv4.w};

    float m[8] = {}, Mv[8] = {};
#pragma unroll
    for (int e = 0; e < 4; ++e) {
        float s = ks[e] * (1.0f / 32.0f);
        float v = vs[e];
        float p = 1.0f;
#pragma unroll
        for (int n = 0; n < 8; ++n) {
            m[n] += p;
            Mv[n] = fmaf(p, v, Mv[n]);
            p *= s;
        }
    }
#pragma unroll
    for (int off = 32; off; off >>= 1)
#pragma unroll
        for (int n = 0; n < 8; ++n) {
            m[n]  += __shfl_xor(m[n],  off, 64);
            Mv[n] += __shfl_xor(Mv[n], off, 64);
        }
    const int wave = tid >> 6;
    if ((tid & 63) == 0) {
#pragma unroll
        for (int n = 0; n < 8; ++n) {
            red[wave][n]     = m[n];
            red[wave][n + 8] = Mv[n];
        }
    }
    __syncthreads();
    if (tid < 16) {
        const float invfact[8] = {1.f, 1.f, 0.5f, 1.f/6.f, 1.f/24.f,
                                  1.f/120.f, 1.f/720.f, 1.f/5040.f};
        sm[tid] = (red[0][tid] + red[1][tid] + red[2][tid] + red[3][tid])
                  * invfact[tid & 7];
    }
    __syncthreads();

    half4 qa = ((const half4*)p0)[tid];
    half4 qb = ((const half4*)p1)[tid];
    half4 o;
#pragma unroll
    for (int e = 0; e < 4; ++e) {
        float c = (float)qa[e] + (float)qb[e];
        float den = sm[7];
#pragma unroll
        for (int n = 6; n >= 0; --n) den = fmaf(den, c, sm[n]);
        float num = sm[15];
#pragma unroll
        for (int n = 14; n >= 8; --n) num = fmaf(num, c, sm[n]);
        o[e] = (_Float16)(num / den);
    }
    ((half4*)attnh)[b * 256 + tid] = o;
}

// ===========================================================================
// out += attn @ Wo^T (bias pre-initialized by attn_kernel). BM=BN=32,
// K-split x2 -> 512 blocks (2/CU), 8 steps (unrolled), f32 atomicAdd
// epilogue (exactly 2 commutative adds per element -> deterministic).
// ===========================================================================
__global__ __launch_bounds__(256) void out_kernel(const _Float16* __restrict__ attnh,
                                                  const float* __restrict__ Wo,
                                                  float* __restrict__ outp)
{
    __shared__ __align__(16) _Float16 sA[2][32 * 64];
    __shared__ __align__(16) _Float16 sB[2][32 * 64];

    const int tid  = threadIdx.x;
    const int lane = tid & 63;
    const int w    = tid >> 6;
    const int wr   = w >> 1, wc = w & 1;
    const int fr   = lane & 15, fg = lane >> 4;

    // 512 = 8 xcd * 64 jobs; job = {16 bm (fast) x 4 bn}; kz = xcd&1
    const int d   = blockIdx.x;
    const int xcd = d & 7;
    const int j   = d >> 3;                  // 0..63
    const int kz  = xcd & 1;
    const int bm  = (j & 15) * 32;
    const int bn  = ((xcd >> 1) * 4 + (j >> 4)) * 32;   // 0..480
    const int k0  = kz * 512;

    const int srow = tid >> 3;
    const int cg_  = tid & 7;
    const _Float16* Ap = attnh + (size_t)(bm + srow) * H_ + k0 + cg_ * 8;
    const float*    Bp = Wo    + (size_t)(bn + srow) * H_ + k0 + cg_ * 8;

    const int sw    = (cg_ ^ (srow & 7)) << 3;
    const int wbase = srow * 64;

    f32x4 acc = {};

    half8  a0 = *(const half8*)Ap;
    float4 b0 = *(const float4*)(Bp + 0), b1 = *(const float4*)(Bp + 4);

#pragma unroll
    for (int t = 0; t < 8; ++t) {
        const int buf = t & 1;
        half8 hA = a0;
        half8 hB = cvt8(b0, b1);
        if (t < 7) {
            a0 = *(const half8*)(Ap + (t + 1) * 64);
            b0 = *(const float4*)(Bp + (t + 1) * 64);
            b1 = *(const float4*)(Bp + (t + 1) * 64 + 4);
        }
        *(half8*)&sA[buf][wbase + sw] = hA;
        *(half8*)&sB[buf][wbase + sw] = hB;
        barrier_nodrain();

#pragma unroll
        for (int kh = 0; kh < 2; ++kh) {
            const int p = (((kh * 4 + fg) ^ (fr & 7)) << 3);
            half8 af = *(const half8*)&sA[buf][(wr * 16 + fr) * 64 + p];
            half8 bf = *(const half8*)&sB[buf][(wc * 16 + fr) * 64 + p];
            acc = __builtin_amdgcn_mfma_f32_16x16x32_f16(af, bf, acc, 0, 0, 0);
        }
    }

    const int row0 = bm + wr * 16 + fg * 4;
    const int col  = bn + wc * 16 + fr;
#pragma unroll
    for (int r = 0; r < 4; ++r)
        atomicAdd(&outp[(size_t)(row0 + r) * OUT_ + col], acc[r]);
}

extern "C" void kernel_launch(void* const* d_in, const int* in_sizes, int n_in,
                              void* d_out, int out_size, void* d_ws, size_t ws_size,
                              hipStream_t stream)
{
    const float* x  = (const float*)d_in[0];
    const float* Wq = (const float*)d_in[1];
    const float* Wk = (const float*)d_in[2];
    const float* Wv = (const float*)d_in[3];
    const float* bv = (const float*)d_in[4];
    const float* Wo = (const float*)d_in[5];
    const float* bo = (const float*)d_in[6];
    float* out = (float*)d_out;

    char* ws = (char*)d_ws;
    _Float16* qkvph = (_Float16*)ws;                 // [2][512][3072] f16 = 6.3 MB
    _Float16* attnh = (_Float16*)(ws + (8 << 20));   // [512][1024] f16 = 1 MB

    qkv_kernel<<<dim3(768), 256, 0, stream>>>(x, Wq, Wk, Wv, qkvph);
    attn_kernel<<<dim3(B_), 256, 0, stream>>>(qkvph, bv, bo, attnh, out);
    out_kernel<<<dim3(512), 256, 0, stream>>>(attnh, Wo, out);
}